// Round 14
// baseline (173.576 us; speedup 1.0000x reference)
//
#include <hip/hip_runtime.h>

typedef unsigned short u16;
typedef unsigned int u32;
typedef __attribute__((ext_vector_type(8))) short bf16x8;
typedef __attribute__((ext_vector_type(4))) float f32x4;
typedef __attribute__((ext_vector_type(4))) u32 u32x4;
typedef __attribute__((ext_vector_type(2))) u32 u32x2;

__device__ __forceinline__ u16 f2bf(float f) {
  u32 u = __builtin_bit_cast(u32, f);
  return (u16)((u + 0x7FFFu + ((u >> 16) & 1u)) >> 16);
}
__device__ __forceinline__ float bf2f(u16 b) {
  return __builtin_bit_cast(float, (u32)b << 16);
}

// v_cvt_pk_bf16_f32 = RNE, bitwise-identical to f2bf for finite inputs
// (proven: r6 fused gemm1 kept absmax exactly 0.001953125).
__device__ __forceinline__ u32 cvtpk(float lo, float hi) {
  u32 r;
  asm("v_cvt_pk_bf16_f32 %0, %1, %2" : "=v"(r) : "v"(lo), "v"(hi));
  return r;
}

__device__ __forceinline__ float fexp2(float x) {
#if __has_builtin(__builtin_amdgcn_exp2f)
  return __builtin_amdgcn_exp2f(x);
#else
  return __expf(x * 0.6931471805599453f);
#endif
}

__device__ __forceinline__ void lds_async16(const void* g, void* l) {
  auto gp = reinterpret_cast<const __attribute__((address_space(1))) u32*>(
      reinterpret_cast<uintptr_t>(g));
  auto lp = reinterpret_cast<__attribute__((address_space(3))) u32*>(
      reinterpret_cast<uintptr_t>(l));
  __builtin_amdgcn_global_load_lds(gp, lp, 16, 0, 0);
}

// combine two ows slabs into packed bf16 (overlap-add); bitwise identical to
// the old combine_kernel + gemm path (sc folded into the gemm epilogue).
__device__ __forceinline__ u32x4 combine_pair(u32x4 a0, u32x4 a1, bool has0, bool has1) {
  if (has0 && has1) {
    u32x4 w;
#pragma unroll
    for (int q = 0; q < 4; ++q) {
      float e = __builtin_bit_cast(float, a0[q] << 16) +
                __builtin_bit_cast(float, a1[q] << 16);
      float o = __builtin_bit_cast(float, a0[q] & 0xFFFF0000u) +
                __builtin_bit_cast(float, a1[q] & 0xFFFF0000u);
      w[q] = cvtpk(e, o);
    }
    return w;
  }
  return has0 ? a0 : a1;
}

// two small weight converts in one launch
__global__ void cvt2_kernel(const float* __restrict__ a, const float* __restrict__ b,
                            u16* __restrict__ oa, u16* __restrict__ ob, int na4, int nb4) {
  int i = blockIdx.x * 256 + threadIdx.x;
  const float* src;
  u16* dst;
  int idx;
  if (i < na4) {
    src = a; dst = oa; idx = i;
  } else {
    idx = i - na4;
    if (idx >= nb4) return;
    src = b; dst = ob;
  }
  f32x4 v = *(const f32x4*)(src + (size_t)idx * 4);
  u32x2 o;
  o[0] = (u32)f2bf(v[0]) | ((u32)f2bf(v[1]) << 16);
  o[1] = (u32)f2bf(v[2]) | ((u32)f2bf(v[3]) << 16);
  *(u32x2*)(dst + (size_t)idx * 4) = o;
}

// ---------------- GEMM1 pipelined: qkv = x @ w_in^T + b_in, bf16 out --------
// PROVEN r12 version (gemm1 46.3 -> ~40us, absmax exact). Single barrier per
// k-step, sA/sB double-buffered (32KB).
// LEDGER r9 (FAILED, 73us): A direct-from-global with NO prefetch distance =
// pure stall. Prefetch DISTANCE is the lever, not LDS removal.
// Operand swap mfma(bfr, af) produced absmax 1.01 — permanently banned.
__global__ __launch_bounds__(256) void gemm1_pipe_kernel(
    const float* __restrict__ A, const u16* __restrict__ B,
    const float* __restrict__ bias, u16* __restrict__ C,
    int M, int N, int K) {
  __shared__ u16 sA[2][128 * 32];
  __shared__ u16 sB[2][128 * 32];
  const int tid = threadIdx.x;
  const int m0 = blockIdx.x * 128;
  const int n0 = blockIdx.y * 128;
  const int w = tid >> 6;
  const int lane = tid & 63;
  const int wr = (w >> 1) * 64;
  const int wc = (w & 1) * 64;
  const int lm = lane & 15;
  const int lk = (lane >> 4) * 8;

  f32x4 acc[4][4] = {};

  const int srow = tid >> 2;
  const int ssub = (tid & 3) * 8;
  const float* Agf = A + (size_t)(m0 + srow) * K + ssub;
  const u16* Bg = B + (size_t)(n0 + srow) * K + ssub;
  const size_t rstep = (size_t)64 * K;

  // prologue: stage tile 0 into buf 0
  {
    f32x4 p00 = *(const f32x4*)(Agf);
    f32x4 p01 = *(const f32x4*)(Agf + 4);
    f32x4 p10 = *(const f32x4*)(Agf + rstep);
    f32x4 p11 = *(const f32x4*)(Agf + rstep + 4);
    u32x4 w0, w1;
    w0[0] = cvtpk(p00[0], p00[1]); w0[1] = cvtpk(p00[2], p00[3]);
    w0[2] = cvtpk(p01[0], p01[1]); w0[3] = cvtpk(p01[2], p01[3]);
    w1[0] = cvtpk(p10[0], p10[1]); w1[1] = cvtpk(p10[2], p10[3]);
    w1[2] = cvtpk(p11[0], p11[1]); w1[3] = cvtpk(p11[2], p11[3]);
    *(u32x4*)&sA[0][tid * 8] = w0;
    *(u32x4*)&sA[0][2048 + tid * 8] = w1;
    lds_async16(Bg, &sB[0][tid * 8]);
    lds_async16(Bg + rstep, &sB[0][2048 + tid * 8]);
  }

  const int nt = K >> 5;
  for (int t = 0; t < nt; ++t) {
    const int cur = t & 1;
    const int nxt = cur ^ 1;
    __syncthreads();  // buf[cur] staged; prev iter's reads of buf[nxt] done
    const bool more = (t + 1 < nt);
    f32x4 n00, n01, n10, n11;
    if (more) {
      const int k1 = (t + 1) * 32;
      n00 = *(const f32x4*)(Agf + k1);
      n01 = *(const f32x4*)(Agf + k1 + 4);
      n10 = *(const f32x4*)(Agf + rstep + k1);
      n11 = *(const f32x4*)(Agf + rstep + k1 + 4);
    }
    bf16x8 af[4], bfr[4];
#pragma unroll
    for (int i = 0; i < 4; ++i)
      af[i] = *(const bf16x8*)&sA[cur][(wr + i * 16 + lm) * 32 + lk];
#pragma unroll
    for (int j = 0; j < 4; ++j)
      bfr[j] = *(const bf16x8*)&sB[cur][(wc + j * 16 + lm) * 32 + lk];
#pragma unroll
    for (int i = 0; i < 4; ++i)
#pragma unroll
      for (int j = 0; j < 4; ++j)
        acc[i][j] = __builtin_amdgcn_mfma_f32_16x16x32_bf16(af[i], bfr[j], acc[i][j], 0, 0, 0);
    if (more) {
      const int k1 = (t + 1) * 32;
      u32x4 w0, w1;
      w0[0] = cvtpk(n00[0], n00[1]); w0[1] = cvtpk(n00[2], n00[3]);
      w0[2] = cvtpk(n01[0], n01[1]); w0[3] = cvtpk(n01[2], n01[3]);
      w1[0] = cvtpk(n10[0], n10[1]); w1[1] = cvtpk(n10[2], n10[3]);
      w1[2] = cvtpk(n11[0], n11[1]); w1[3] = cvtpk(n11[2], n11[3]);
      *(u32x4*)&sA[nxt][tid * 8] = w0;
      *(u32x4*)&sA[nxt][2048 + tid * 8] = w1;
      lds_async16(Bg + k1, &sB[nxt][tid * 8]);
      lds_async16(Bg + rstep + k1, &sB[nxt][2048 + tid * 8]);
    }
  }

  const int r0 = (lane >> 4) * 4;
#pragma unroll
  for (int j = 0; j < 4; ++j) {
    const int n = n0 + wc + j * 16 + lm;
    const float bv = bias[n];
#pragma unroll
    for (int i = 0; i < 4; ++i) {
#pragma unroll
      for (int r = 0; r < 4; ++r) {
        const int m = m0 + wr + i * 16 + r0 + r;
        C[(size_t)m * N + n] = f2bf(acc[i][j][r] + bv);
      }
    }
  }
}

// ---------------- GEMM2 fused+pipelined: y = combine(ows) @ w_out^T + b_out --
// r13 version (neutral vs r11's 2-barrier — gemm2 is A-bytes-bound, pipeline
// didn't change bytes; kept, not harmful). combine fused into A-staging,
// sc=0.5 folded into the epilogue fmaf (bitwise-exact). Do not swap mfma
// operand order.
__global__ __launch_bounds__(256) void gemm2_pipe_kernel(
    const u16* __restrict__ ows, const u16* __restrict__ B,
    const float* __restrict__ bias, float* __restrict__ C,
    int M, int N, int K) {
  __shared__ u16 sA[2][128 * 32];
  __shared__ u16 sB[2][128 * 32];
  const int tid = threadIdx.x;
  const int x = blockIdx.x;
  const int m0 = x * 128;
  const int n0 = blockIdx.y * 128;
  const int bc = x / 33;
  const int ib = x - bc * 33;          // = i0, block-uniform
  const bool has0 = (ib <= 31);
  const bool has1 = (ib >= 1);
  const float sc = (has0 && has1) ? 0.5f : 1.0f;
  const int w = tid >> 6;
  const int lane = tid & 63;
  const int wr = (w >> 1) * 64;
  const int wc = (w & 1) * 64;
  const int lm = lane & 15;
  const int lk = (lane >> 4) * 8;

  f32x4 acc[4][4] = {};

  const int srow = tid >> 2;
  const int ssub = (tid & 3) * 8;
  const u16* A0 = ows + ((size_t)((bc * 32 + ib) * 256 + srow)) * 256 + ssub;
  const u16* A1 = ows + ((size_t)((bc * 32 + ib - 1) * 256 + 128 + srow)) * 256 + ssub;
  const size_t arstep = (size_t)64 * 256;
  const u16* Bg = B + (size_t)(n0 + srow) * K + ssub;
  const size_t rstep = (size_t)64 * K;

  // prologue: stage tile 0 into buf 0
  {
    u32x4 a00{}, a01{}, a10{}, a11{};
    if (has0) {
      a00 = *(const u32x4*)(A0);
      a01 = *(const u32x4*)(A0 + arstep);
    }
    if (has1) {
      a10 = *(const u32x4*)(A1);
      a11 = *(const u32x4*)(A1 + arstep);
    }
    *(u32x4*)&sA[0][tid * 8] = combine_pair(a00, a10, has0, has1);
    *(u32x4*)&sA[0][2048 + tid * 8] = combine_pair(a01, a11, has0, has1);
    lds_async16(Bg, &sB[0][tid * 8]);
    lds_async16(Bg + rstep, &sB[0][2048 + tid * 8]);
  }

  const int nt = K >> 5;
  for (int t = 0; t < nt; ++t) {
    const int cur = t & 1;
    const int nxt = cur ^ 1;
    __syncthreads();  // buf[cur] staged; prev iter's reads of buf[nxt] done
    const bool more = (t + 1 < nt);
    u32x4 n00{}, n01{}, n10{}, n11{};
    if (more) {
      const int k1 = (t + 1) * 32;
      if (has0) {
        n00 = *(const u32x4*)(A0 + k1);
        n01 = *(const u32x4*)(A0 + arstep + k1);
      }
      if (has1) {
        n10 = *(const u32x4*)(A1 + k1);
        n11 = *(const u32x4*)(A1 + arstep + k1);
      }
    }
    bf16x8 af[4], bfr[4];
#pragma unroll
    for (int i = 0; i < 4; ++i)
      af[i] = *(const bf16x8*)&sA[cur][(wr + i * 16 + lm) * 32 + lk];
#pragma unroll
    for (int j = 0; j < 4; ++j)
      bfr[j] = *(const bf16x8*)&sB[cur][(wc + j * 16 + lm) * 32 + lk];
#pragma unroll
    for (int i = 0; i < 4; ++i)
#pragma unroll
      for (int j = 0; j < 4; ++j)
        acc[i][j] = __builtin_amdgcn_mfma_f32_16x16x32_bf16(af[i], bfr[j], acc[i][j], 0, 0, 0);
    if (more) {
      const int k1 = (t + 1) * 32;
      *(u32x4*)&sA[nxt][tid * 8] = combine_pair(n00, n10, has0, has1);
      *(u32x4*)&sA[nxt][2048 + tid * 8] = combine_pair(n01, n11, has0, has1);
      lds_async16(Bg + k1, &sB[nxt][tid * 8]);
      lds_async16(Bg + rstep + k1, &sB[nxt][2048 + tid * 8]);
    }
  }

  const int r0 = (lane >> 4) * 4;
#pragma unroll
  for (int j = 0; j < 4; ++j) {
    const int n = n0 + wc + j * 16 + lm;
    const float bv = bias[n];
#pragma unroll
    for (int i = 0; i < 4; ++i) {
#pragma unroll
      for (int r = 0; r < 4; ++r) {
        const int m = m0 + wr + i * 16 + r0 + r;
        C[(size_t)m * N + n] = __builtin_fmaf(sc, acc[i][j][r], bv);
      }
    }
  }
}

// ---------------- fused per-(block,head) attention ----------------
// r2-exact math/structure; ROUND-14 change: V staged in TWO j-halves so
// sVt shrinks 32x264 -> 32x136 (stride 136: dword-stride 68 == 4 mod 32,
// same bank spread as the proven 132). LDS 27136 -> 18944 B.
// THEORY: occupancy has tracked LDS like a ~64KB residency pool
// (27136->30%, 37376->24%); kernel is VALU/TRANS(exp2)-bound at ~2.4
// resident blocks, so +1 block/CU raises issue density. Restage at ch==4
// behind a barrier pair; vf column becomes (ch&3)*32+lg*8 (XOR swizzle
// unchanged, stays <128). Same staged values -> bitwise-identical output.
// LEDGER (measured):
//  r2 44.9us: sVt col XOR-swizzle; cvt_pk packing; denominator via
//    mfma(P, ones); 1-deep K prefetch; setprio; single sP + WAR fence.
//  r3 48.0us REGRESSED: sP hf-dbuf + V-reg-prefetch -> VGPR 68 crossed the
//    64-VGPR allocation cliff (8->7 waves/SIMD), occ 31->24%.
//  r4 48.0us: sP-XOR changed conflict count by exactly 0 -> conflicts are
//    NOT sP. LESSON: stay at VGPR <= 64.
//  r5 FAILED (absmax 0.19): K-row re-tiling. OPEN MYSTERY — needs disasm.
// launch_bounds(256,2): (256,4) spilled catastrophically. `#pragma unroll 1`
// on the ch loop is load-bearing. The asm memory fence pins the P-tile
// read -> overwrite (WAR) order.
__global__ __launch_bounds__(256, 2) void attn_kernel(const u16* __restrict__ qkv,
                                                      u16* __restrict__ o_ws) {
  __shared__ u16 sVt[32 * 136];   // V transposed, HALF of j at a time
  __shared__ u16 sP[4 * 32 * 40]; // per-wave P half-tile: 32 rows x 40 u16

  const int bid = blockIdx.x;
  const int n = bid >> 3;
  const int h = bid & 7;
  const int rowbase = (n >> 5) * 4224 + (n & 31) * 128;
  const int tid = threadIdx.x;
  const int w = tid >> 6;
  const int lane = tid & 63;
  const int lm = lane & 15;
  const int lg = lane >> 4;

  // stage one j-half of V transposed: V[j0+row][d] -> sVt[d*136 + (row^((d>>3)<<4))]
  auto stageV = [&](int j0) {
#pragma unroll
    for (int it = 0; it < 2; ++it) {
      int c = it * 256 + tid;
      int row = c >> 2;              // 0..127
      int sub = (c & 3) * 8;
      int rsw = row ^ ((sub >> 3) << 4);   // (d>>3) is sub>>3 for all 8 d
      const u16* gv = qkv + (size_t)(rowbase + j0 + row) * 768 + 512 + h * 32 + sub;
      u32x4 vv = *(const u32x4*)gv;
#pragma unroll
      for (int q = 0; q < 4; ++q) {
        sVt[(sub + 2 * q) * 136 + rsw] = (u16)(vv[q] & 0xFFFFu);
        sVt[(sub + 2 * q + 1) * 136 + rsw] = (u16)(vv[q] >> 16);
      }
    }
  };
  stageV(0);

  // Q fragments straight from global (wave-private rows; 16 rows x 64B contiguous)
  bf16x8 qf[4];
#pragma unroll
  for (int rt = 0; rt < 4; ++rt) {
    int row = rowbase + w * 64 + rt * 16 + lm;
    qf[rt] = *(const bf16x8*)(qkv + (size_t)row * 768 + h * 32 + lg * 8);
  }

  const u16* kbase = qkv + (size_t)(rowbase + lm) * 768 + 256 + h * 32 + lg * 8;

  // prime K prefetch for ch=0 (overlaps the staging barrier)
  bf16x8 kfc[2];
#pragma unroll
  for (int ct = 0; ct < 2; ++ct)
    kfc[ct] = *(const bf16x8*)(kbase + (size_t)(ct * 16) * 768);

  __syncthreads();

  f32x4 oacc[4][2] = {};
  f32x4 lacc[4] = {};   // softmax denominators via mfma(P, ones)
  u16* myP = sP + w * (32 * 40);
  const float C1 = 0.25500035370494726f; // scale * log2(e)
  const float C2 = 1.4426950408889634f;  // log2(e)
  const int jq = lg * 4;
  const int D0w = w * 64;
  const bf16x8 onesb = {(short)0x3F80, (short)0x3F80, (short)0x3F80, (short)0x3F80,
                        (short)0x3F80, (short)0x3F80, (short)0x3F80, (short)0x3F80};

#pragma unroll 1
  for (int ch = 0; ch < 8; ++ch) {
    if (ch == 4) {
      __syncthreads();   // all waves done reading V half-1
      stageV(128);
      __syncthreads();   // V half-2 ready
    }
    // prefetch next chunk's K fragments (clamped; last iter loads are dead)
    const int chn = (ch < 7) ? ch + 1 : 7;
    bf16x8 kfn[2], vf[2];
#pragma unroll
    for (int ct = 0; ct < 2; ++ct)
      kfn[ct] = *(const bf16x8*)(kbase + (size_t)(chn * 32 + ct * 16) * 768);
#pragma unroll
    for (int ctd = 0; ctd < 2; ++ctd) {
      int d = ctd * 16 + lm;
      vf[ctd] = *(const bf16x8*)&sVt[d * 136 + (((ch & 3) * 32 + lg * 8) ^ ((d >> 3) << 4))];
    }

#pragma unroll
    for (int hf = 0; hf < 2; ++hf) {
#pragma unroll
      for (int ct = 0; ct < 2; ++ct) {
#pragma unroll
        for (int rl = 0; rl < 2; ++rl) {
          const int rt = hf * 2 + rl;
          f32x4 s = __builtin_amdgcn_mfma_f32_16x16x32_bf16(kfc[ct], qf[rt], f32x4{0.f, 0.f, 0.f, 0.f}, 0, 0, 0);
          const int D0 = D0w + rt * 16 - (ch * 32 + ct * 16); // wave-uniform
          float p0, p1, p2, p3;
          if (D0 >= 16 && D0 <= 112) {        // fully in-band: +1 bias
            p0 = fexp2(__builtin_fmaf(s[0], C1, C2));
            p1 = fexp2(__builtin_fmaf(s[1], C1, C2));
            p2 = fexp2(__builtin_fmaf(s[2], C1, C2));
            p3 = fexp2(__builtin_fmaf(s[3], C1, C2));
          } else if (D0 == 0) {               // diagonal: in-band iff lm >= jq+r
            p0 = fexp2(__builtin_fmaf(s[0], C1, (lm >= jq + 0) ? C2 : 0.0f));
            p1 = fexp2(__builtin_fmaf(s[1], C1, (lm >= jq + 1) ? C2 : 0.0f));
            p2 = fexp2(__builtin_fmaf(s[2], C1, (lm >= jq + 2) ? C2 : 0.0f));
            p3 = fexp2(__builtin_fmaf(s[3], C1, (lm >= jq + 3) ? C2 : 0.0f));
          } else if (D0 == 128) {             // far edge: in-band iff lm < jq+r
            p0 = fexp2(__builtin_fmaf(s[0], C1, (lm < jq + 0) ? C2 : 0.0f));
            p1 = fexp2(__builtin_fmaf(s[1], C1, (lm < jq + 1) ? C2 : 0.0f));
            p2 = fexp2(__builtin_fmaf(s[2], C1, (lm < jq + 2) ? C2 : 0.0f));
            p3 = fexp2(__builtin_fmaf(s[3], C1, (lm < jq + 3) ? C2 : 0.0f));
          } else {                            // fully out of band: no bias
            p0 = fexp2(s[0] * C1);
            p1 = fexp2(s[1] * C1);
            p2 = fexp2(s[2] * C1);
            p3 = fexp2(s[3] * C1);
          }
          u32 a0, a1;
          asm("v_cvt_pk_bf16_f32 %0, %1, %2" : "=v"(a0) : "v"(p0), "v"(p1));
          asm("v_cvt_pk_bf16_f32 %0, %1, %2" : "=v"(a1) : "v"(p2), "v"(p3));
          u32x2 pk;
          pk[0] = a0;
          pk[1] = a1;
          *(u32x2*)&myP[(rl * 16 + lm) * 40 + ct * 16 + jq] = pk;
        }
      }
      // O(half) += P(half) * Vc ; lsum(half) += P(half) . 1  (wave-private P)
      bf16x8 pf[2];
#pragma unroll
      for (int rl = 0; rl < 2; ++rl)
        pf[rl] = *(const bf16x8*)&myP[(rl * 16 + lm) * 40 + lg * 8];
      // pin WAR order: these reads must precede the next half's overwrites
      __asm__ __volatile__("" ::: "memory");
      __builtin_amdgcn_s_setprio(1);
#pragma unroll
      for (int rl = 0; rl < 2; ++rl) {
        lacc[hf * 2 + rl] =
            __builtin_amdgcn_mfma_f32_16x16x32_bf16(pf[rl], onesb, lacc[hf * 2 + rl], 0, 0, 0);
#pragma unroll
        for (int ctd = 0; ctd < 2; ++ctd)
          oacc[hf * 2 + rl][ctd] =
              __builtin_amdgcn_mfma_f32_16x16x32_bf16(pf[rl], vf[ctd], oacc[hf * 2 + rl][ctd], 0, 0, 0);
      }
      __builtin_amdgcn_s_setprio(0);
    }
    kfc[0] = kfn[0];
    kfc[1] = kfn[1];
  }

  // normalize + store; lacc[rt][r] holds the full denominator for row
  // i = rt*16 + lg*4 + r (C/D layout row = lg*4+r), exactly the epilogue row.
#pragma unroll
  for (int rt = 0; rt < 4; ++rt) {
#pragma unroll
    for (int r = 0; r < 4; ++r) {
      float inv = 1.0f / lacc[rt][r];
      int i_g = w * 64 + rt * 16 + jq + r;
#pragma unroll
      for (int ctd = 0; ctd < 2; ++ctd) {
        float v = oacc[rt][ctd][r] * inv;
        u32 u = __builtin_bit_cast(u32, v) + 0x8000u;
        o_ws[((size_t)(n * 256 + i_g)) * 256 + h * 32 + ctd * 16 + lm] = (u16)(u >> 16);
      }
    }
  }
}

extern "C" void kernel_launch(void* const* d_in, const int* in_sizes, int n_in,
                              void* d_out, int out_size, void* d_ws, size_t ws_size,
                              hipStream_t stream) {
  const float* x = (const float*)d_in[0];
  const float* w_in = (const float*)d_in[1];
  const float* b_in = (const float*)d_in[2];
  const float* w_out = (const float*)d_in[3];
  const float* b_out = (const float*)d_in[4];
  float* y = (float*)d_out;
  char* ws = (char*)d_ws;

  // workspace layout (bytes)
  u16* qkv = (u16*)(ws);                   // 33792*768*2   = 51,904,512
  u16* ows = (u16*)(ws + 69206016);        // 256*256*256*2 = 33,554,432
  u16* winb = (u16*)(ws + 102760448);      // 768*256*2     = 393,216
  u16* woutb = (u16*)(ws + 103153664);     // 256*256*2     = 131,072  (end 103,284,736)

  cvt2_kernel<<<256, 256, 0, stream>>>(w_in, w_out, winb, woutb, 49152, 16384);

  // qkv = x @ w_in^T + b_in — pipelined: A f32 reg-prefetch + sA/sB dbuf,
  // one barrier per k-step
  gemm1_pipe_kernel<<<dim3(264, 6), 256, 0, stream>>>(x, winb, b_in, qkv, 33792, 768, 256);

  // per-(block, head) attention
  attn_kernel<<<2048, 256, 0, stream>>>(qkv, ows);

  // y = combine(ows) @ w_out^T + b_out — combine fused into A-staging
  gemm2_pipe_kernel<<<dim3(264, 2), 256, 0, stream>>>(ows, woutb, b_out, y, 33792, 256, 256);
}

// Round 15
// 170.006 us; speedup vs baseline: 1.0210x; 1.0210x over previous
//
#include <hip/hip_runtime.h>

typedef unsigned short u16;
typedef unsigned int u32;
typedef __attribute__((ext_vector_type(8))) short bf16x8;
typedef __attribute__((ext_vector_type(4))) float f32x4;
typedef __attribute__((ext_vector_type(4))) u32 u32x4;
typedef __attribute__((ext_vector_type(2))) u32 u32x2;

__device__ __forceinline__ u16 f2bf(float f) {
  u32 u = __builtin_bit_cast(u32, f);
  return (u16)((u + 0x7FFFu + ((u >> 16) & 1u)) >> 16);
}
__device__ __forceinline__ float bf2f(u16 b) {
  return __builtin_bit_cast(float, (u32)b << 16);
}

// v_cvt_pk_bf16_f32 = RNE, bitwise-identical to f2bf for finite inputs
// (proven: r6 fused gemm1 kept absmax exactly 0.001953125).
__device__ __forceinline__ u32 cvtpk(float lo, float hi) {
  u32 r;
  asm("v_cvt_pk_bf16_f32 %0, %1, %2" : "=v"(r) : "v"(lo), "v"(hi));
  return r;
}

__device__ __forceinline__ float fexp2(float x) {
#if __has_builtin(__builtin_amdgcn_exp2f)
  return __builtin_amdgcn_exp2f(x);
#else
  return __expf(x * 0.6931471805599453f);
#endif
}

__device__ __forceinline__ void lds_async16(const void* g, void* l) {
  auto gp = reinterpret_cast<const __attribute__((address_space(1))) u32*>(
      reinterpret_cast<uintptr_t>(g));
  auto lp = reinterpret_cast<__attribute__((address_space(3))) u32*>(
      reinterpret_cast<uintptr_t>(l));
  __builtin_amdgcn_global_load_lds(gp, lp, 16, 0, 0);
}

// combine two ows slabs into packed bf16 (overlap-add); bitwise identical to
// the old combine_kernel + gemm path (sc folded into the gemm epilogue).
__device__ __forceinline__ u32x4 combine_pair(u32x4 a0, u32x4 a1, bool has0, bool has1) {
  if (has0 && has1) {
    u32x4 w;
#pragma unroll
    for (int q = 0; q < 4; ++q) {
      float e = __builtin_bit_cast(float, a0[q] << 16) +
                __builtin_bit_cast(float, a1[q] << 16);
      float o = __builtin_bit_cast(float, a0[q] & 0xFFFF0000u) +
                __builtin_bit_cast(float, a1[q] & 0xFFFF0000u);
      w[q] = cvtpk(e, o);
    }
    return w;
  }
  return has0 ? a0 : a1;
}

// two small weight converts in one launch
__global__ void cvt2_kernel(const float* __restrict__ a, const float* __restrict__ b,
                            u16* __restrict__ oa, u16* __restrict__ ob, int na4, int nb4) {
  int i = blockIdx.x * 256 + threadIdx.x;
  const float* src;
  u16* dst;
  int idx;
  if (i < na4) {
    src = a; dst = oa; idx = i;
  } else {
    idx = i - na4;
    if (idx >= nb4) return;
    src = b; dst = ob;
  }
  f32x4 v = *(const f32x4*)(src + (size_t)idx * 4);
  u32x2 o;
  o[0] = (u32)f2bf(v[0]) | ((u32)f2bf(v[1]) << 16);
  o[1] = (u32)f2bf(v[2]) | ((u32)f2bf(v[3]) << 16);
  *(u32x2*)(dst + (size_t)idx * 4) = o;
}

// ---------------- GEMM1 pipelined: qkv = x @ w_in^T + b_in, bf16 out --------
// PROVEN r12 version (gemm1 46.3 -> ~40us, absmax exact). Single barrier per
// k-step, sA/sB double-buffered (32KB).
// LEDGER r9 (FAILED, 73us): A direct-from-global with NO prefetch distance =
// pure stall. Prefetch DISTANCE is the lever, not LDS removal.
// Operand swap mfma(bfr, af) produced absmax 1.01 — permanently banned.
__global__ __launch_bounds__(256) void gemm1_pipe_kernel(
    const float* __restrict__ A, const u16* __restrict__ B,
    const float* __restrict__ bias, u16* __restrict__ C,
    int M, int N, int K) {
  __shared__ u16 sA[2][128 * 32];
  __shared__ u16 sB[2][128 * 32];
  const int tid = threadIdx.x;
  const int m0 = blockIdx.x * 128;
  const int n0 = blockIdx.y * 128;
  const int w = tid >> 6;
  const int lane = tid & 63;
  const int wr = (w >> 1) * 64;
  const int wc = (w & 1) * 64;
  const int lm = lane & 15;
  const int lk = (lane >> 4) * 8;

  f32x4 acc[4][4] = {};

  const int srow = tid >> 2;
  const int ssub = (tid & 3) * 8;
  const float* Agf = A + (size_t)(m0 + srow) * K + ssub;
  const u16* Bg = B + (size_t)(n0 + srow) * K + ssub;
  const size_t rstep = (size_t)64 * K;

  // prologue: stage tile 0 into buf 0
  {
    f32x4 p00 = *(const f32x4*)(Agf);
    f32x4 p01 = *(const f32x4*)(Agf + 4);
    f32x4 p10 = *(const f32x4*)(Agf + rstep);
    f32x4 p11 = *(const f32x4*)(Agf + rstep + 4);
    u32x4 w0, w1;
    w0[0] = cvtpk(p00[0], p00[1]); w0[1] = cvtpk(p00[2], p00[3]);
    w0[2] = cvtpk(p01[0], p01[1]); w0[3] = cvtpk(p01[2], p01[3]);
    w1[0] = cvtpk(p10[0], p10[1]); w1[1] = cvtpk(p10[2], p10[3]);
    w1[2] = cvtpk(p11[0], p11[1]); w1[3] = cvtpk(p11[2], p11[3]);
    *(u32x4*)&sA[0][tid * 8] = w0;
    *(u32x4*)&sA[0][2048 + tid * 8] = w1;
    lds_async16(Bg, &sB[0][tid * 8]);
    lds_async16(Bg + rstep, &sB[0][2048 + tid * 8]);
  }

  const int nt = K >> 5;
  for (int t = 0; t < nt; ++t) {
    const int cur = t & 1;
    const int nxt = cur ^ 1;
    __syncthreads();  // buf[cur] staged; prev iter's reads of buf[nxt] done
    const bool more = (t + 1 < nt);
    f32x4 n00, n01, n10, n11;
    if (more) {
      const int k1 = (t + 1) * 32;
      n00 = *(const f32x4*)(Agf + k1);
      n01 = *(const f32x4*)(Agf + k1 + 4);
      n10 = *(const f32x4*)(Agf + rstep + k1);
      n11 = *(const f32x4*)(Agf + rstep + k1 + 4);
    }
    bf16x8 af[4], bfr[4];
#pragma unroll
    for (int i = 0; i < 4; ++i)
      af[i] = *(const bf16x8*)&sA[cur][(wr + i * 16 + lm) * 32 + lk];
#pragma unroll
    for (int j = 0; j < 4; ++j)
      bfr[j] = *(const bf16x8*)&sB[cur][(wc + j * 16 + lm) * 32 + lk];
#pragma unroll
    for (int i = 0; i < 4; ++i)
#pragma unroll
      for (int j = 0; j < 4; ++j)
        acc[i][j] = __builtin_amdgcn_mfma_f32_16x16x32_bf16(af[i], bfr[j], acc[i][j], 0, 0, 0);
    if (more) {
      const int k1 = (t + 1) * 32;
      u32x4 w0, w1;
      w0[0] = cvtpk(n00[0], n00[1]); w0[1] = cvtpk(n00[2], n00[3]);
      w0[2] = cvtpk(n01[0], n01[1]); w0[3] = cvtpk(n01[2], n01[3]);
      w1[0] = cvtpk(n10[0], n10[1]); w1[1] = cvtpk(n10[2], n10[3]);
      w1[2] = cvtpk(n11[0], n11[1]); w1[3] = cvtpk(n11[2], n11[3]);
      *(u32x4*)&sA[nxt][tid * 8] = w0;
      *(u32x4*)&sA[nxt][2048 + tid * 8] = w1;
      lds_async16(Bg + k1, &sB[nxt][tid * 8]);
      lds_async16(Bg + rstep + k1, &sB[nxt][2048 + tid * 8]);
    }
  }

  const int r0 = (lane >> 4) * 4;
#pragma unroll
  for (int j = 0; j < 4; ++j) {
    const int n = n0 + wc + j * 16 + lm;
    const float bv = bias[n];
#pragma unroll
    for (int i = 0; i < 4; ++i) {
#pragma unroll
      for (int r = 0; r < 4; ++r) {
        const int m = m0 + wr + i * 16 + r0 + r;
        C[(size_t)m * N + n] = f2bf(acc[i][j][r] + bv);
      }
    }
  }
}

// ---------------- GEMM2 fused+pipelined: y = combine(ows) @ w_out^T + b_out --
// r13 version (neutral vs r11's 2-barrier — gemm2 is A-bytes-bound; kept).
// combine fused into A-staging, sc=0.5 folded into the epilogue fmaf
// (bitwise-exact). Do not swap mfma operand order.
__global__ __launch_bounds__(256) void gemm2_pipe_kernel(
    const u16* __restrict__ ows, const u16* __restrict__ B,
    const float* __restrict__ bias, float* __restrict__ C,
    int M, int N, int K) {
  __shared__ u16 sA[2][128 * 32];
  __shared__ u16 sB[2][128 * 32];
  const int tid = threadIdx.x;
  const int x = blockIdx.x;
  const int m0 = x * 128;
  const int n0 = blockIdx.y * 128;
  const int bc = x / 33;
  const int ib = x - bc * 33;          // = i0, block-uniform
  const bool has0 = (ib <= 31);
  const bool has1 = (ib >= 1);
  const float sc = (has0 && has1) ? 0.5f : 1.0f;
  const int w = tid >> 6;
  const int lane = tid & 63;
  const int wr = (w >> 1) * 64;
  const int wc = (w & 1) * 64;
  const int lm = lane & 15;
  const int lk = (lane >> 4) * 8;

  f32x4 acc[4][4] = {};

  const int srow = tid >> 2;
  const int ssub = (tid & 3) * 8;
  const u16* A0 = ows + ((size_t)((bc * 32 + ib) * 256 + srow)) * 256 + ssub;
  const u16* A1 = ows + ((size_t)((bc * 32 + ib - 1) * 256 + 128 + srow)) * 256 + ssub;
  const size_t arstep = (size_t)64 * 256;
  const u16* Bg = B + (size_t)(n0 + srow) * K + ssub;
  const size_t rstep = (size_t)64 * K;

  // prologue: stage tile 0 into buf 0
  {
    u32x4 a00{}, a01{}, a10{}, a11{};
    if (has0) {
      a00 = *(const u32x4*)(A0);
      a01 = *(const u32x4*)(A0 + arstep);
    }
    if (has1) {
      a10 = *(const u32x4*)(A1);
      a11 = *(const u32x4*)(A1 + arstep);
    }
    *(u32x4*)&sA[0][tid * 8] = combine_pair(a00, a10, has0, has1);
    *(u32x4*)&sA[0][2048 + tid * 8] = combine_pair(a01, a11, has0, has1);
    lds_async16(Bg, &sB[0][tid * 8]);
    lds_async16(Bg + rstep, &sB[0][2048 + tid * 8]);
  }

  const int nt = K >> 5;
  for (int t = 0; t < nt; ++t) {
    const int cur = t & 1;
    const int nxt = cur ^ 1;
    __syncthreads();  // buf[cur] staged; prev iter's reads of buf[nxt] done
    const bool more = (t + 1 < nt);
    u32x4 n00{}, n01{}, n10{}, n11{};
    if (more) {
      const int k1 = (t + 1) * 32;
      if (has0) {
        n00 = *(const u32x4*)(A0 + k1);
        n01 = *(const u32x4*)(A0 + arstep + k1);
      }
      if (has1) {
        n10 = *(const u32x4*)(A1 + k1);
        n11 = *(const u32x4*)(A1 + arstep + k1);
      }
    }
    bf16x8 af[4], bfr[4];
#pragma unroll
    for (int i = 0; i < 4; ++i)
      af[i] = *(const bf16x8*)&sA[cur][(wr + i * 16 + lm) * 32 + lk];
#pragma unroll
    for (int j = 0; j < 4; ++j)
      bfr[j] = *(const bf16x8*)&sB[cur][(wc + j * 16 + lm) * 32 + lk];
#pragma unroll
    for (int i = 0; i < 4; ++i)
#pragma unroll
      for (int j = 0; j < 4; ++j)
        acc[i][j] = __builtin_amdgcn_mfma_f32_16x16x32_bf16(af[i], bfr[j], acc[i][j], 0, 0, 0);
    if (more) {
      const int k1 = (t + 1) * 32;
      *(u32x4*)&sA[nxt][tid * 8] = combine_pair(n00, n10, has0, has1);
      *(u32x4*)&sA[nxt][2048 + tid * 8] = combine_pair(n01, n11, has0, has1);
      lds_async16(Bg + k1, &sB[nxt][tid * 8]);
      lds_async16(Bg + rstep + k1, &sB[nxt][2048 + tid * 8]);
    }
  }

  const int r0 = (lane >> 4) * 4;
#pragma unroll
  for (int j = 0; j < 4; ++j) {
    const int n = n0 + wc + j * 16 + lm;
    const float bv = bias[n];
#pragma unroll
    for (int i = 0; i < 4; ++i) {
#pragma unroll
      for (int r = 0; r < 4; ++r) {
        const int m = m0 + wr + i * 16 + r0 + r;
        C[(size_t)m * N + n] = __builtin_fmaf(sc, acc[i][j][r], bv);
      }
    }
  }
}

// ---------------- fused per-(block,head) attention ----------------
// ROUND-2 EXACT SOURCE (proven 44.3-44.9us, VGPR 64). FINAL — do not touch.
// LEDGER (measured, 5 structural attempts, 4 regressed/failed):
//  r2 44.9us: sVt col XOR-swizzle; cvt_pk packing; denominator via
//    mfma(P, ones); 1-deep K prefetch; setprio; single sP + WAR fence.
//  r3 48.0us REGRESSED: sP hf-dbuf + V-reg-prefetch -> VGPR 68 crossed the
//    64-VGPR allocation cliff (8->7 waves/SIMD), occ 31->24%.
//  r4 48.0us: sP-XOR changed conflict count by exactly 0 -> conflicts are
//    NOT sP. LESSON: stay at VGPR <= 64.
//  r5 FAILED (absmax 0.19): K-row re-tiling. OPEN MYSTERY — needs disasm.
//  r14 50.0us REGRESSED: V staged in 2 halves (LDS 27136->18944) -> lambda/
//    restage pushed VGPR 64->68, occ 30->24%, FETCH +9MB. The 64-VGPR cliff
//    eats any structural edit; r2 is a measured local optimum.
// launch_bounds(256,2): (256,4) spilled catastrophically. `#pragma unroll 1`
// on the ch loop is load-bearing. The asm memory fence pins the P-tile
// read -> overwrite (WAR) order.
__global__ __launch_bounds__(256, 2) void attn_kernel(const u16* __restrict__ qkv,
                                                      u16* __restrict__ o_ws) {
  __shared__ u16 sVt[32 * 264];   // V transposed, stride 264 u16, cols XOR-swizzled
  __shared__ u16 sP[4 * 32 * 40]; // per-wave P half-tile: 32 rows x 40 u16

  const int bid = blockIdx.x;
  const int n = bid >> 3;
  const int h = bid & 7;
  const int rowbase = (n >> 5) * 4224 + (n & 31) * 128;
  const int tid = threadIdx.x;
  const int w = tid >> 6;
  const int lane = tid & 63;
  const int lm = lane & 15;
  const int lg = lane >> 4;

  // stage V transposed for this head: V[j][d] -> sVt[d*264 + (j ^ ((d>>3)<<4))]
#pragma unroll
  for (int it = 0; it < 4; ++it) {
    int c = it * 256 + tid;
    int row = c >> 2;
    int sub = (c & 3) * 8;
    int rsw = row ^ ((sub >> 3) << 4);   // swizzled column; (d>>3) is sub>>3 for all 8 d
    const u16* gv = qkv + (size_t)(rowbase + row) * 768 + 512 + h * 32 + sub;
    u32x4 vv = *(const u32x4*)gv;
#pragma unroll
    for (int q = 0; q < 4; ++q) {
      sVt[(sub + 2 * q) * 264 + rsw] = (u16)(vv[q] & 0xFFFFu);
      sVt[(sub + 2 * q + 1) * 264 + rsw] = (u16)(vv[q] >> 16);
    }
  }

  // Q fragments straight from global (wave-private rows; 16 rows x 64B contiguous)
  bf16x8 qf[4];
#pragma unroll
  for (int rt = 0; rt < 4; ++rt) {
    int row = rowbase + w * 64 + rt * 16 + lm;
    qf[rt] = *(const bf16x8*)(qkv + (size_t)row * 768 + h * 32 + lg * 8);
  }

  const u16* kbase = qkv + (size_t)(rowbase + lm) * 768 + 256 + h * 32 + lg * 8;

  // prime K prefetch for ch=0 (overlaps the staging barrier)
  bf16x8 kfc[2];
#pragma unroll
  for (int ct = 0; ct < 2; ++ct)
    kfc[ct] = *(const bf16x8*)(kbase + (size_t)(ct * 16) * 768);

  __syncthreads();

  f32x4 oacc[4][2] = {};
  f32x4 lacc[4] = {};   // softmax denominators via mfma(P, ones)
  u16* myP = sP + w * (32 * 40);
  const float C1 = 0.25500035370494726f; // scale * log2(e)
  const float C2 = 1.4426950408889634f;  // log2(e)
  const int jq = lg * 4;
  const int D0w = w * 64;
  const bf16x8 onesb = {(short)0x3F80, (short)0x3F80, (short)0x3F80, (short)0x3F80,
                        (short)0x3F80, (short)0x3F80, (short)0x3F80, (short)0x3F80};

#pragma unroll 1
  for (int ch = 0; ch < 8; ++ch) {
    // prefetch next chunk's K fragments (clamped; last iter loads are dead)
    const int chn = (ch < 7) ? ch + 1 : 7;
    bf16x8 kfn[2], vf[2];
#pragma unroll
    for (int ct = 0; ct < 2; ++ct)
      kfn[ct] = *(const bf16x8*)(kbase + (size_t)(chn * 32 + ct * 16) * 768);
#pragma unroll
    for (int ctd = 0; ctd < 2; ++ctd) {
      int d = ctd * 16 + lm;
      vf[ctd] = *(const bf16x8*)&sVt[d * 264 + ((ch * 32 + lg * 8) ^ ((d >> 3) << 4))];
    }

#pragma unroll
    for (int hf = 0; hf < 2; ++hf) {
#pragma unroll
      for (int ct = 0; ct < 2; ++ct) {
#pragma unroll
        for (int rl = 0; rl < 2; ++rl) {
          const int rt = hf * 2 + rl;
          f32x4 s = __builtin_amdgcn_mfma_f32_16x16x32_bf16(kfc[ct], qf[rt], f32x4{0.f, 0.f, 0.f, 0.f}, 0, 0, 0);
          const int D0 = D0w + rt * 16 - (ch * 32 + ct * 16); // wave-uniform
          float p0, p1, p2, p3;
          if (D0 >= 16 && D0 <= 112) {        // fully in-band: +1 bias
            p0 = fexp2(__builtin_fmaf(s[0], C1, C2));
            p1 = fexp2(__builtin_fmaf(s[1], C1, C2));
            p2 = fexp2(__builtin_fmaf(s[2], C1, C2));
            p3 = fexp2(__builtin_fmaf(s[3], C1, C2));
          } else if (D0 == 0) {               // diagonal: in-band iff lm >= jq+r
            p0 = fexp2(__builtin_fmaf(s[0], C1, (lm >= jq + 0) ? C2 : 0.0f));
            p1 = fexp2(__builtin_fmaf(s[1], C1, (lm >= jq + 1) ? C2 : 0.0f));
            p2 = fexp2(__builtin_fmaf(s[2], C1, (lm >= jq + 2) ? C2 : 0.0f));
            p3 = fexp2(__builtin_fmaf(s[3], C1, (lm >= jq + 3) ? C2 : 0.0f));
          } else if (D0 == 128) {             // far edge: in-band iff lm < jq+r
            p0 = fexp2(__builtin_fmaf(s[0], C1, (lm < jq + 0) ? C2 : 0.0f));
            p1 = fexp2(__builtin_fmaf(s[1], C1, (lm < jq + 1) ? C2 : 0.0f));
            p2 = fexp2(__builtin_fmaf(s[2], C1, (lm < jq + 2) ? C2 : 0.0f));
            p3 = fexp2(__builtin_fmaf(s[3], C1, (lm < jq + 3) ? C2 : 0.0f));
          } else {                            // fully out of band: no bias
            p0 = fexp2(s[0] * C1);
            p1 = fexp2(s[1] * C1);
            p2 = fexp2(s[2] * C1);
            p3 = fexp2(s[3] * C1);
          }
          u32 a0, a1;
          asm("v_cvt_pk_bf16_f32 %0, %1, %2" : "=v"(a0) : "v"(p0), "v"(p1));
          asm("v_cvt_pk_bf16_f32 %0, %1, %2" : "=v"(a1) : "v"(p2), "v"(p3));
          u32x2 pk;
          pk[0] = a0;
          pk[1] = a1;
          *(u32x2*)&myP[(rl * 16 + lm) * 40 + ct * 16 + jq] = pk;
        }
      }
      // O(half) += P(half) * Vc ; lsum(half) += P(half) . 1  (wave-private P)
      bf16x8 pf[2];
#pragma unroll
      for (int rl = 0; rl < 2; ++rl)
        pf[rl] = *(const bf16x8*)&myP[(rl * 16 + lm) * 40 + lg * 8];
      // pin WAR order: these reads must precede the next half's overwrites
      __asm__ __volatile__("" ::: "memory");
      __builtin_amdgcn_s_setprio(1);
#pragma unroll
      for (int rl = 0; rl < 2; ++rl) {
        lacc[hf * 2 + rl] =
            __builtin_amdgcn_mfma_f32_16x16x32_bf16(pf[rl], onesb, lacc[hf * 2 + rl], 0, 0, 0);
#pragma unroll
        for (int ctd = 0; ctd < 2; ++ctd)
          oacc[hf * 2 + rl][ctd] =
              __builtin_amdgcn_mfma_f32_16x16x32_bf16(pf[rl], vf[ctd], oacc[hf * 2 + rl][ctd], 0, 0, 0);
      }
      __builtin_amdgcn_s_setprio(0);
    }
    kfc[0] = kfn[0];
    kfc[1] = kfn[1];
  }

  // normalize + store; lacc[rt][r] holds the full denominator for row
  // i = rt*16 + lg*4 + r (C/D layout row = lg*4+r), exactly the epilogue row.
#pragma unroll
  for (int rt = 0; rt < 4; ++rt) {
#pragma unroll
    for (int r = 0; r < 4; ++r) {
      float inv = 1.0f / lacc[rt][r];
      int i_g = w * 64 + rt * 16 + jq + r;
#pragma unroll
      for (int ctd = 0; ctd < 2; ++ctd) {
        float v = oacc[rt][ctd][r] * inv;
        u32 u = __builtin_bit_cast(u32, v) + 0x8000u;
        o_ws[((size_t)(n * 256 + i_g)) * 256 + h * 32 + ctd * 16 + lm] = (u16)(u >> 16);
      }
    }
  }
}

extern "C" void kernel_launch(void* const* d_in, const int* in_sizes, int n_in,
                              void* d_out, int out_size, void* d_ws, size_t ws_size,
                              hipStream_t stream) {
  const float* x = (const float*)d_in[0];
  const float* w_in = (const float*)d_in[1];
  const float* b_in = (const float*)d_in[2];
  const float* w_out = (const float*)d_in[3];
  const float* b_out = (const float*)d_in[4];
  float* y = (float*)d_out;
  char* ws = (char*)d_ws;

  // workspace layout (bytes)
  u16* qkv = (u16*)(ws);                   // 33792*768*2   = 51,904,512
  u16* ows = (u16*)(ws + 69206016);        // 256*256*256*2 = 33,554,432
  u16* winb = (u16*)(ws + 102760448);      // 768*256*2     = 393,216
  u16* woutb = (u16*)(ws + 103153664);     // 256*256*2     = 131,072  (end 103,284,736)

  cvt2_kernel<<<256, 256, 0, stream>>>(w_in, w_out, winb, woutb, 49152, 16384);

  // qkv = x @ w_in^T + b_in — pipelined: A f32 reg-prefetch + sA/sB dbuf,
  // one barrier per k-step
  gemm1_pipe_kernel<<<dim3(264, 6), 256, 0, stream>>>(x, winb, b_in, qkv, 33792, 768, 256);

  // per-(block, head) attention
  attn_kernel<<<2048, 256, 0, stream>>>(qkv, ows);

  // y = combine(ows) @ w_out^T + b_out — combine fused into A-staging
  gemm2_pipe_kernel<<<dim3(264, 2), 256, 0, stream>>>(ows, woutb, b_out, y, 33792, 256, 256);
}

// Round 16
// 166.421 us; speedup vs baseline: 1.0430x; 1.0215x over previous
//
#include <hip/hip_runtime.h>

typedef unsigned short u16;
typedef unsigned int u32;
typedef __attribute__((ext_vector_type(8))) short bf16x8;
typedef __attribute__((ext_vector_type(4))) float f32x4;
typedef __attribute__((ext_vector_type(4))) u32 u32x4;
typedef __attribute__((ext_vector_type(2))) u32 u32x2;

__device__ __forceinline__ u16 f2bf(float f) {
  u32 u = __builtin_bit_cast(u32, f);
  return (u16)((u + 0x7FFFu + ((u >> 16) & 1u)) >> 16);
}
__device__ __forceinline__ float bf2f(u16 b) {
  return __builtin_bit_cast(float, (u32)b << 16);
}

// v_cvt_pk_bf16_f32 = RNE, bitwise-identical to f2bf for finite inputs
// (proven: r6 fused gemm1 kept absmax exactly 0.001953125).
__device__ __forceinline__ u32 cvtpk(float lo, float hi) {
  u32 r;
  asm("v_cvt_pk_bf16_f32 %0, %1, %2" : "=v"(r) : "v"(lo), "v"(hi));
  return r;
}

__device__ __forceinline__ float fexp2(float x) {
#if __has_builtin(__builtin_amdgcn_exp2f)
  return __builtin_amdgcn_exp2f(x);
#else
  return __expf(x * 0.6931471805599453f);
#endif
}

__device__ __forceinline__ void lds_async16(const void* g, void* l) {
  auto gp = reinterpret_cast<const __attribute__((address_space(1))) u32*>(
      reinterpret_cast<uintptr_t>(g));
  auto lp = reinterpret_cast<__attribute__((address_space(3))) u32*>(
      reinterpret_cast<uintptr_t>(l));
  __builtin_amdgcn_global_load_lds(gp, lp, 16, 0, 0);
}

// combine two ows slabs into packed bf16 (overlap-add); bitwise identical to
// the old combine_kernel + gemm path (sc folded into the gemm epilogue).
__device__ __forceinline__ u32x4 combine_pair(u32x4 a0, u32x4 a1, bool has0, bool has1) {
  if (has0 && has1) {
    u32x4 w;
#pragma unroll
    for (int q = 0; q < 4; ++q) {
      float e = __builtin_bit_cast(float, a0[q] << 16) +
                __builtin_bit_cast(float, a1[q] << 16);
      float o = __builtin_bit_cast(float, a0[q] & 0xFFFF0000u) +
                __builtin_bit_cast(float, a1[q] & 0xFFFF0000u);
      w[q] = cvtpk(e, o);
    }
    return w;
  }
  return has0 ? a0 : a1;
}

// two small weight converts in one launch
__global__ void cvt2_kernel(const float* __restrict__ a, const float* __restrict__ b,
                            u16* __restrict__ oa, u16* __restrict__ ob, int na4, int nb4) {
  int i = blockIdx.x * 256 + threadIdx.x;
  const float* src;
  u16* dst;
  int idx;
  if (i < na4) {
    src = a; dst = oa; idx = i;
  } else {
    idx = i - na4;
    if (idx >= nb4) return;
    src = b; dst = ob;
  }
  f32x4 v = *(const f32x4*)(src + (size_t)idx * 4);
  u32x2 o;
  o[0] = (u32)f2bf(v[0]) | ((u32)f2bf(v[1]) << 16);
  o[1] = (u32)f2bf(v[2]) | ((u32)f2bf(v[3]) << 16);
  *(u32x2*)(dst + (size_t)idx * 4) = o;
}

// ---------------- GEMM1 pipelined: qkv = x @ w_in^T + b_in, bf16 out --------
// PROVEN r12 version (gemm1 46.3 -> ~40us, absmax exact). Single barrier per
// k-step, sA/sB double-buffered (32KB).
// LEDGER r9 (FAILED, 73us): A direct-from-global with NO prefetch distance =
// pure stall. Prefetch DISTANCE is the lever, not LDS removal.
// Operand swap mfma(bfr, af) produced absmax 1.01 — permanently banned.
// A-panel reuse across the 6 y-blocks is already L2-local by accident:
// (x,y)->(x,y+1) is 264 apart, 264 % 8 == 0 -> same XCD under round-robin.
__global__ __launch_bounds__(256) void gemm1_pipe_kernel(
    const float* __restrict__ A, const u16* __restrict__ B,
    const float* __restrict__ bias, u16* __restrict__ C,
    int M, int N, int K) {
  __shared__ u16 sA[2][128 * 32];
  __shared__ u16 sB[2][128 * 32];
  const int tid = threadIdx.x;
  const int m0 = blockIdx.x * 128;
  const int n0 = blockIdx.y * 128;
  const int w = tid >> 6;
  const int lane = tid & 63;
  const int wr = (w >> 1) * 64;
  const int wc = (w & 1) * 64;
  const int lm = lane & 15;
  const int lk = (lane >> 4) * 8;

  f32x4 acc[4][4] = {};

  const int srow = tid >> 2;
  const int ssub = (tid & 3) * 8;
  const float* Agf = A + (size_t)(m0 + srow) * K + ssub;
  const u16* Bg = B + (size_t)(n0 + srow) * K + ssub;
  const size_t rstep = (size_t)64 * K;

  // prologue: stage tile 0 into buf 0
  {
    f32x4 p00 = *(const f32x4*)(Agf);
    f32x4 p01 = *(const f32x4*)(Agf + 4);
    f32x4 p10 = *(const f32x4*)(Agf + rstep);
    f32x4 p11 = *(const f32x4*)(Agf + rstep + 4);
    u32x4 w0, w1;
    w0[0] = cvtpk(p00[0], p00[1]); w0[1] = cvtpk(p00[2], p00[3]);
    w0[2] = cvtpk(p01[0], p01[1]); w0[3] = cvtpk(p01[2], p01[3]);
    w1[0] = cvtpk(p10[0], p10[1]); w1[1] = cvtpk(p10[2], p10[3]);
    w1[2] = cvtpk(p11[0], p11[1]); w1[3] = cvtpk(p11[2], p11[3]);
    *(u32x4*)&sA[0][tid * 8] = w0;
    *(u32x4*)&sA[0][2048 + tid * 8] = w1;
    lds_async16(Bg, &sB[0][tid * 8]);
    lds_async16(Bg + rstep, &sB[0][2048 + tid * 8]);
  }

  const int nt = K >> 5;
  for (int t = 0; t < nt; ++t) {
    const int cur = t & 1;
    const int nxt = cur ^ 1;
    __syncthreads();  // buf[cur] staged; prev iter's reads of buf[nxt] done
    const bool more = (t + 1 < nt);
    f32x4 n00, n01, n10, n11;
    if (more) {
      const int k1 = (t + 1) * 32;
      n00 = *(const f32x4*)(Agf + k1);
      n01 = *(const f32x4*)(Agf + k1 + 4);
      n10 = *(const f32x4*)(Agf + rstep + k1);
      n11 = *(const f32x4*)(Agf + rstep + k1 + 4);
    }
    bf16x8 af[4], bfr[4];
#pragma unroll
    for (int i = 0; i < 4; ++i)
      af[i] = *(const bf16x8*)&sA[cur][(wr + i * 16 + lm) * 32 + lk];
#pragma unroll
    for (int j = 0; j < 4; ++j)
      bfr[j] = *(const bf16x8*)&sB[cur][(wc + j * 16 + lm) * 32 + lk];
#pragma unroll
    for (int i = 0; i < 4; ++i)
#pragma unroll
      for (int j = 0; j < 4; ++j)
        acc[i][j] = __builtin_amdgcn_mfma_f32_16x16x32_bf16(af[i], bfr[j], acc[i][j], 0, 0, 0);
    if (more) {
      const int k1 = (t + 1) * 32;
      u32x4 w0, w1;
      w0[0] = cvtpk(n00[0], n00[1]); w0[1] = cvtpk(n00[2], n00[3]);
      w0[2] = cvtpk(n01[0], n01[1]); w0[3] = cvtpk(n01[2], n01[3]);
      w1[0] = cvtpk(n10[0], n10[1]); w1[1] = cvtpk(n10[2], n10[3]);
      w1[2] = cvtpk(n11[0], n11[1]); w1[3] = cvtpk(n11[2], n11[3]);
      *(u32x4*)&sA[nxt][tid * 8] = w0;
      *(u32x4*)&sA[nxt][2048 + tid * 8] = w1;
      lds_async16(Bg + k1, &sB[nxt][tid * 8]);
      lds_async16(Bg + rstep + k1, &sB[nxt][2048 + tid * 8]);
    }
  }

  const int r0 = (lane >> 4) * 4;
#pragma unroll
  for (int j = 0; j < 4; ++j) {
    const int n = n0 + wc + j * 16 + lm;
    const float bv = bias[n];
#pragma unroll
    for (int i = 0; i < 4; ++i) {
#pragma unroll
      for (int r = 0; r < 4; ++r) {
        const int m = m0 + wr + i * 16 + r0 + r;
        C[(size_t)m * N + n] = f2bf(acc[i][j][r] + bv);
      }
    }
  }
}

// ---------------- GEMM2 fused+pipelined: y = combine(ows) @ w_out^T + b_out --
// r13 version (neutral vs r11's 2-barrier — gemm2 is A-bytes-bound; kept).
// combine fused into A-staging, sc=0.5 folded into the epilogue fmaf
// (bitwise-exact). Do not swap mfma operand order.
__global__ __launch_bounds__(256) void gemm2_pipe_kernel(
    const u16* __restrict__ ows, const u16* __restrict__ B,
    const float* __restrict__ bias, float* __restrict__ C,
    int M, int N, int K) {
  __shared__ u16 sA[2][128 * 32];
  __shared__ u16 sB[2][128 * 32];
  const int tid = threadIdx.x;
  const int x = blockIdx.x;
  const int m0 = x * 128;
  const int n0 = blockIdx.y * 128;
  const int bc = x / 33;
  const int ib = x - bc * 33;          // = i0, block-uniform
  const bool has0 = (ib <= 31);
  const bool has1 = (ib >= 1);
  const float sc = (has0 && has1) ? 0.5f : 1.0f;
  const int w = tid >> 6;
  const int lane = tid & 63;
  const int wr = (w >> 1) * 64;
  const int wc = (w & 1) * 64;
  const int lm = lane & 15;
  const int lk = (lane >> 4) * 8;

  f32x4 acc[4][4] = {};

  const int srow = tid >> 2;
  const int ssub = (tid & 3) * 8;
  const u16* A0 = ows + ((size_t)((bc * 32 + ib) * 256 + srow)) * 256 + ssub;
  const u16* A1 = ows + ((size_t)((bc * 32 + ib - 1) * 256 + 128 + srow)) * 256 + ssub;
  const size_t arstep = (size_t)64 * 256;
  const u16* Bg = B + (size_t)(n0 + srow) * K + ssub;
  const size_t rstep = (size_t)64 * K;

  // prologue: stage tile 0 into buf 0
  {
    u32x4 a00{}, a01{}, a10{}, a11{};
    if (has0) {
      a00 = *(const u32x4*)(A0);
      a01 = *(const u32x4*)(A0 + arstep);
    }
    if (has1) {
      a10 = *(const u32x4*)(A1);
      a11 = *(const u32x4*)(A1 + arstep);
    }
    *(u32x4*)&sA[0][tid * 8] = combine_pair(a00, a10, has0, has1);
    *(u32x4*)&sA[0][2048 + tid * 8] = combine_pair(a01, a11, has0, has1);
    lds_async16(Bg, &sB[0][tid * 8]);
    lds_async16(Bg + rstep, &sB[0][2048 + tid * 8]);
  }

  const int nt = K >> 5;
  for (int t = 0; t < nt; ++t) {
    const int cur = t & 1;
    const int nxt = cur ^ 1;
    __syncthreads();  // buf[cur] staged; prev iter's reads of buf[nxt] done
    const bool more = (t + 1 < nt);
    u32x4 n00{}, n01{}, n10{}, n11{};
    if (more) {
      const int k1 = (t + 1) * 32;
      if (has0) {
        n00 = *(const u32x4*)(A0 + k1);
        n01 = *(const u32x4*)(A0 + arstep + k1);
      }
      if (has1) {
        n10 = *(const u32x4*)(A1 + k1);
        n11 = *(const u32x4*)(A1 + arstep + k1);
      }
    }
    bf16x8 af[4], bfr[4];
#pragma unroll
    for (int i = 0; i < 4; ++i)
      af[i] = *(const bf16x8*)&sA[cur][(wr + i * 16 + lm) * 32 + lk];
#pragma unroll
    for (int j = 0; j < 4; ++j)
      bfr[j] = *(const bf16x8*)&sB[cur][(wc + j * 16 + lm) * 32 + lk];
#pragma unroll
    for (int i = 0; i < 4; ++i)
#pragma unroll
      for (int j = 0; j < 4; ++j)
        acc[i][j] = __builtin_amdgcn_mfma_f32_16x16x32_bf16(af[i], bfr[j], acc[i][j], 0, 0, 0);
    if (more) {
      const int k1 = (t + 1) * 32;
      *(u32x4*)&sA[nxt][tid * 8] = combine_pair(n00, n10, has0, has1);
      *(u32x4*)&sA[nxt][2048 + tid * 8] = combine_pair(n01, n11, has0, has1);
      lds_async16(Bg + k1, &sB[nxt][tid * 8]);
      lds_async16(Bg + rstep + k1, &sB[nxt][2048 + tid * 8]);
    }
  }

  const int r0 = (lane >> 4) * 4;
#pragma unroll
  for (int j = 0; j < 4; ++j) {
    const int n = n0 + wc + j * 16 + lm;
    const float bv = bias[n];
#pragma unroll
    for (int i = 0; i < 4; ++i) {
#pragma unroll
      for (int r = 0; r < 4; ++r) {
        const int m = m0 + wr + i * 16 + r0 + r;
        C[(size_t)m * N + n] = __builtin_fmaf(sc, acc[i][j][r], bv);
      }
    }
  }
}

// ---------------- fused per-(block,head) attention ----------------
// ROUND-2 EXACT body (proven 44.3-44.9us, VGPR 64). ROUND-16 change is ONLY
// the block-id -> (n,h) remap (XCD-aware, T1):
//   old: bid = n*8 + h (h fastest) -> the 8 head-blocks sharing one 196KB
//        qkv panel are consecutive -> round-robin onto 8 DIFFERENT XCDs ->
//        each XCD fetches the panel into its private L2 separately.
//   new: bid = j + 8h + 64*n_local  (j = n>>5 = XCD digit), inverse
//        n = (bid&7)*32 + (bid>>6), h = (bid>>3)&7. Bijective (8/8/32
//        digits). Under round-robin, XCD j executes "8 h's of one n, then
//        next n" -> panel fetched once, L2-hot for all 8 heads. Working set
//        ~8 panels x 196KB = 1.6MB < 4MB L2. Scalar-only remap: no VGPR
//        change, bitwise-identical output. If XCD mapping differs, speed-
//        neutral, never incorrect.
// LEDGER (measured, 5 structural attempts, 4 regressed/failed):
//  r2 44.9us: sVt col XOR-swizzle; cvt_pk packing; denominator via
//    mfma(P, ones); 1-deep K prefetch; setprio; single sP + WAR fence.
//  r3 48.0us REGRESSED: sP hf-dbuf + V-reg-prefetch -> VGPR 68 crossed the
//    64-VGPR allocation cliff (8->7 waves/SIMD).
//  r4 48.0us: sP-XOR changed conflict count by exactly 0 -> conflicts are
//    NOT sP. LESSON: stay at VGPR <= 64.
//  r5 FAILED (absmax 0.19): K-row re-tiling. OPEN MYSTERY — needs disasm.
//  r14 50.0us REGRESSED: V 2-half staging -> VGPR 64->68 cliff + FETCH +9MB.
//  NOTE: OccupancyPercent is computed with gfx94x (64KB-LDS) formulas on
//  gfx950 — treat as unreliable; r14's "LDS pool" theory was this artifact.
// launch_bounds(256,2): (256,4) spilled catastrophically. `#pragma unroll 1`
// on the ch loop is load-bearing. The asm memory fence pins the P-tile
// read -> overwrite (WAR) order.
__global__ __launch_bounds__(256, 2) void attn_kernel(const u16* __restrict__ qkv,
                                                      u16* __restrict__ o_ws) {
  __shared__ u16 sVt[32 * 264];   // V transposed, stride 264 u16, cols XOR-swizzled
  __shared__ u16 sP[4 * 32 * 40]; // per-wave P half-tile: 32 rows x 40 u16

  const int bid = blockIdx.x;
  const int n = ((bid & 7) << 5) | (bid >> 6);   // XCD-aware remap (r16)
  const int h = (bid >> 3) & 7;
  const int rowbase = (n >> 5) * 4224 + (n & 31) * 128;
  const int tid = threadIdx.x;
  const int w = tid >> 6;
  const int lane = tid & 63;
  const int lm = lane & 15;
  const int lg = lane >> 4;

  // stage V transposed for this head: V[j][d] -> sVt[d*264 + (j ^ ((d>>3)<<4))]
#pragma unroll
  for (int it = 0; it < 4; ++it) {
    int c = it * 256 + tid;
    int row = c >> 2;
    int sub = (c & 3) * 8;
    int rsw = row ^ ((sub >> 3) << 4);   // swizzled column; (d>>3) is sub>>3 for all 8 d
    const u16* gv = qkv + (size_t)(rowbase + row) * 768 + 512 + h * 32 + sub;
    u32x4 vv = *(const u32x4*)gv;
#pragma unroll
    for (int q = 0; q < 4; ++q) {
      sVt[(sub + 2 * q) * 264 + rsw] = (u16)(vv[q] & 0xFFFFu);
      sVt[(sub + 2 * q + 1) * 264 + rsw] = (u16)(vv[q] >> 16);
    }
  }

  // Q fragments straight from global (wave-private rows; 16 rows x 64B contiguous)
  bf16x8 qf[4];
#pragma unroll
  for (int rt = 0; rt < 4; ++rt) {
    int row = rowbase + w * 64 + rt * 16 + lm;
    qf[rt] = *(const bf16x8*)(qkv + (size_t)row * 768 + h * 32 + lg * 8);
  }

  const u16* kbase = qkv + (size_t)(rowbase + lm) * 768 + 256 + h * 32 + lg * 8;

  // prime K prefetch for ch=0 (overlaps the staging barrier)
  bf16x8 kfc[2];
#pragma unroll
  for (int ct = 0; ct < 2; ++ct)
    kfc[ct] = *(const bf16x8*)(kbase + (size_t)(ct * 16) * 768);

  __syncthreads();

  f32x4 oacc[4][2] = {};
  f32x4 lacc[4] = {};   // softmax denominators via mfma(P, ones)
  u16* myP = sP + w * (32 * 40);
  const float C1 = 0.25500035370494726f; // scale * log2(e)
  const float C2 = 1.4426950408889634f;  // log2(e)
  const int jq = lg * 4;
  const int D0w = w * 64;
  const bf16x8 onesb = {(short)0x3F80, (short)0x3F80, (short)0x3F80, (short)0x3F80,
                        (short)0x3F80, (short)0x3F80, (short)0x3F80, (short)0x3F80};

#pragma unroll 1
  for (int ch = 0; ch < 8; ++ch) {
    // prefetch next chunk's K fragments (clamped; last iter loads are dead)
    const int chn = (ch < 7) ? ch + 1 : 7;
    bf16x8 kfn[2], vf[2];
#pragma unroll
    for (int ct = 0; ct < 2; ++ct)
      kfn[ct] = *(const bf16x8*)(kbase + (size_t)(chn * 32 + ct * 16) * 768);
#pragma unroll
    for (int ctd = 0; ctd < 2; ++ctd) {
      int d = ctd * 16 + lm;
      vf[ctd] = *(const bf16x8*)&sVt[d * 264 + ((ch * 32 + lg * 8) ^ ((d >> 3) << 4))];
    }

#pragma unroll
    for (int hf = 0; hf < 2; ++hf) {
#pragma unroll
      for (int ct = 0; ct < 2; ++ct) {
#pragma unroll
        for (int rl = 0; rl < 2; ++rl) {
          const int rt = hf * 2 + rl;
          f32x4 s = __builtin_amdgcn_mfma_f32_16x16x32_bf16(kfc[ct], qf[rt], f32x4{0.f, 0.f, 0.f, 0.f}, 0, 0, 0);
          const int D0 = D0w + rt * 16 - (ch * 32 + ct * 16); // wave-uniform
          float p0, p1, p2, p3;
          if (D0 >= 16 && D0 <= 112) {        // fully in-band: +1 bias
            p0 = fexp2(__builtin_fmaf(s[0], C1, C2));
            p1 = fexp2(__builtin_fmaf(s[1], C1, C2));
            p2 = fexp2(__builtin_fmaf(s[2], C1, C2));
            p3 = fexp2(__builtin_fmaf(s[3], C1, C2));
          } else if (D0 == 0) {               // diagonal: in-band iff lm >= jq+r
            p0 = fexp2(__builtin_fmaf(s[0], C1, (lm >= jq + 0) ? C2 : 0.0f));
            p1 = fexp2(__builtin_fmaf(s[1], C1, (lm >= jq + 1) ? C2 : 0.0f));
            p2 = fexp2(__builtin_fmaf(s[2], C1, (lm >= jq + 2) ? C2 : 0.0f));
            p3 = fexp2(__builtin_fmaf(s[3], C1, (lm >= jq + 3) ? C2 : 0.0f));
          } else if (D0 == 128) {             // far edge: in-band iff lm < jq+r
            p0 = fexp2(__builtin_fmaf(s[0], C1, (lm < jq + 0) ? C2 : 0.0f));
            p1 = fexp2(__builtin_fmaf(s[1], C1, (lm < jq + 1) ? C2 : 0.0f));
            p2 = fexp2(__builtin_fmaf(s[2], C1, (lm < jq + 2) ? C2 : 0.0f));
            p3 = fexp2(__builtin_fmaf(s[3], C1, (lm < jq + 3) ? C2 : 0.0f));
          } else {                            // fully out of band: no bias
            p0 = fexp2(s[0] * C1);
            p1 = fexp2(s[1] * C1);
            p2 = fexp2(s[2] * C1);
            p3 = fexp2(s[3] * C1);
          }
          u32 a0, a1;
          asm("v_cvt_pk_bf16_f32 %0, %1, %2" : "=v"(a0) : "v"(p0), "v"(p1));
          asm("v_cvt_pk_bf16_f32 %0, %1, %2" : "=v"(a1) : "v"(p2), "v"(p3));
          u32x2 pk;
          pk[0] = a0;
          pk[1] = a1;
          *(u32x2*)&myP[(rl * 16 + lm) * 40 + ct * 16 + jq] = pk;
        }
      }
      // O(half) += P(half) * Vc ; lsum(half) += P(half) . 1  (wave-private P)
      bf16x8 pf[2];
#pragma unroll
      for (int rl = 0; rl < 2; ++rl)
        pf[rl] = *(const bf16x8*)&myP[(rl * 16 + lm) * 40 + lg * 8];
      // pin WAR order: these reads must precede the next half's overwrites
      __asm__ __volatile__("" ::: "memory");
      __builtin_amdgcn_s_setprio(1);
#pragma unroll
      for (int rl = 0; rl < 2; ++rl) {
        lacc[hf * 2 + rl] =
            __builtin_amdgcn_mfma_f32_16x16x32_bf16(pf[rl], onesb, lacc[hf * 2 + rl], 0, 0, 0);
#pragma unroll
        for (int ctd = 0; ctd < 2; ++ctd)
          oacc[hf * 2 + rl][ctd] =
              __builtin_amdgcn_mfma_f32_16x16x32_bf16(pf[rl], vf[ctd], oacc[hf * 2 + rl][ctd], 0, 0, 0);
      }
      __builtin_amdgcn_s_setprio(0);
    }
    kfc[0] = kfn[0];
    kfc[1] = kfn[1];
  }

  // normalize + store; lacc[rt][r] holds the full denominator for row
  // i = rt*16 + lg*4 + r (C/D layout row = lg*4+r), exactly the epilogue row.
#pragma unroll
  for (int rt = 0; rt < 4; ++rt) {
#pragma unroll
    for (int r = 0; r < 4; ++r) {
      float inv = 1.0f / lacc[rt][r];
      int i_g = w * 64 + rt * 16 + jq + r;
#pragma unroll
      for (int ctd = 0; ctd < 2; ++ctd) {
        float v = oacc[rt][ctd][r] * inv;
        u32 u = __builtin_bit_cast(u32, v) + 0x8000u;
        o_ws[((size_t)(n * 256 + i_g)) * 256 + h * 32 + ctd * 16 + lm] = (u16)(u >> 16);
      }
    }
  }
}

extern "C" void kernel_launch(void* const* d_in, const int* in_sizes, int n_in,
                              void* d_out, int out_size, void* d_ws, size_t ws_size,
                              hipStream_t stream) {
  const float* x = (const float*)d_in[0];
  const float* w_in = (const float*)d_in[1];
  const float* b_in = (const float*)d_in[2];
  const float* w_out = (const float*)d_in[3];
  const float* b_out = (const float*)d_in[4];
  float* y = (float*)d_out;
  char* ws = (char*)d_ws;

  // workspace layout (bytes)
  u16* qkv = (u16*)(ws);                   // 33792*768*2   = 51,904,512
  u16* ows = (u16*)(ws + 69206016);        // 256*256*256*2 = 33,554,432
  u16* winb = (u16*)(ws + 102760448);      // 768*256*2     = 393,216
  u16* woutb = (u16*)(ws + 103153664);     // 256*256*2     = 131,072  (end 103,284,736)

  cvt2_kernel<<<256, 256, 0, stream>>>(w_in, w_out, winb, woutb, 49152, 16384);

  // qkv = x @ w_in^T + b_in — pipelined: A f32 reg-prefetch + sA/sB dbuf,
  // one barrier per k-step
  gemm1_pipe_kernel<<<dim3(264, 6), 256, 0, stream>>>(x, winb, b_in, qkv, 33792, 768, 256);

  // per-(block, head) attention (XCD-aware block remap inside)
  attn_kernel<<<2048, 256, 0, stream>>>(qkv, ows);

  // y = combine(ows) @ w_out^T + b_out — combine fused into A-staging
  gemm2_pipe_kernel<<<dim3(264, 2), 256, 0, stream>>>(ows, woutb, b_out, y, 33792, 256, 256);
}